// Round 9
// baseline (426.160 us; speedup 1.0000x reference)
//
#include <hip/hip_runtime.h>
#include <math.h>

#define EPS 1e-9f

constexpr int B_ = 8, N_ = 2048, M_ = 2048;
constexpr int THREADS = 512;               // 8 waves/block
constexpr int WAVES = 8;
constexpr int RPW = 4;                     // rows per wave (wave-uniform rows!)
constexpr int RPB = WAVES * RPW;           // 32 rows per block
constexpr int BPB = N_ / RPB;              // 64 blocks per batch
constexpr int GRID = B_ * BPB;             // 512 blocks = 2/CU

__global__ __launch_bounds__(256) void init_kernel(float* rL, float* fb,
                                                   float* ss0, float* out) {
    int i = blockIdx.x * blockDim.x + threadIdx.x;
    if (i < B_ * N_) { rL[i] = 1.f; fb[i] = 0.f; ss0[i] = 0.f; }
    if (i < B_) out[i] = 0.f;
}

// Merged sort (round-8, measured off the critical top-5): key+index bitonic,
// wave-local phases barrier-free, 16 blocks (both arrays concurrent).
__global__ __launch_bounds__(1024) void sort_kernel(
        const float* __restrict__ xyz1, const float* __restrict__ xyz2,
        float4* __restrict__ out1, float4* __restrict__ out2,
        float2* __restrict__ bounds) {
    __shared__ float kx[2048];
    __shared__ int   ki[2048];
    const int bb = blockIdx.x;
    const bool isB = (bb >= B_);
    const int b = isB ? bb - B_ : bb;
    const float* __restrict__ src = isB ? xyz2 : xyz1;
    float4* __restrict__ dst = isB ? out2 : out1;
    const int t = threadIdx.x;

    for (int i = t; i < 2048; i += 1024) {
        kx[i] = src[((size_t)b * 2048 + i) * 3];
        ki[i] = i;
    }
    __syncthreads();

    bool prev_cross = false;
    for (int ksz = 2; ksz <= 2048; ksz <<= 1) {
        for (int j = ksz >> 1; j >= 1; j >>= 1) {
            const bool cross = (j >= 128);
            if (cross || prev_cross) __syncthreads();
            else __builtin_amdgcn_wave_barrier();
            const int i  = t + (t & ~(j - 1));
            const int pr = i + j;
            const bool up = ((i & ksz) == 0);
            const float ax = kx[i], bx = kx[pr];
            if ((ax > bx) == up) {
                const int ai = ki[i], bi = ki[pr];
                kx[i] = bx; kx[pr] = ax;
                ki[i] = bi; ki[pr] = ai;
            }
            prev_cross = cross;
        }
    }
    __syncthreads();

    for (int i = t; i < 2048; i += 1024) {
        const float* q = src + ((size_t)b * 2048 + ki[i]) * 3;
        dst[(size_t)b * 2048 + i] = make_float4(q[0], q[1], q[2], 0.f);
    }
    if (isB && t < 32)
        bounds[b * 32 + t] = make_float2(kx[t * 64], kx[t * 64 + 63]);
}

// Fused step with exact underflow skipping (round 7/8) + round-9 change:
// DENSE FAST PATHS. When a wave's mask is all-ones (dense levels s>=5, and
// always for s=9/10), run a fully-unrolled k-loop with explicit register
// prefetch of the (k+1) column tile — forces the scheduler to overlap the
// ~120cy ds_read latency with the compute body instead of serializing
// load->wait->compute per k (VGPR was 52: allocator refused ILP; launch
// bounds loosened to (512,1) to hand it the budget). Bit-identical math:
// fast path only taken when the per-k mask branches are provably no-ops.
__global__ __launch_bounds__(THREADS, 1) void fused_step(
        const float4* __restrict__ xyz1s, const float4* __restrict__ xyz2s,
        const float2* __restrict__ bounds2,
        float* __restrict__ rLb, float* __restrict__ fb,
        const float* __restrict__ rRp,   // rR(s-1) in   (unused if !has_p2)
        float* __restrict__ rRn_g,       // rR(s)  out   (designated block)
        const float* __restrict__ ssp_g, // ss(s-1) in   (unused if !has_p2)
        float* __restrict__ ssc_g,       // ss(s) atomic accumulate (pre-zeroed)
        float* __restrict__ ssz_g,       // ss(s+1) zeroed here for next kernel
        float* __restrict__ out,
        float ascale, float inva, int has_p2, int has_p1, int domask, int lcz)
{
    // raw[0:8192)      : sp  = float4 (a*x,a*y,a*z,rn)  32 KB
    // raw[8192:10240)  : sg  = g                         8 KB
    // raw[0:16384)     : ssl overlay (8 waves x 2048)   64 KB after barrier
    // raw[16384:..)    : wcost[8], sfn_l[8], bnds[32] (outside overlay)
    __shared__ __align__(16) float raw[8 * M_ + 2 * WAVES + 64];
    float4* sp    = (float4*)raw;
    float*  sg    = raw + 4 * M_;
    float*  ssl   = raw;
    float*  wcost = raw + 8 * M_;
    float*  sfn_l = raw + 8 * M_ + WAVES;
    float2* bnds  = (float2*)(raw + 8 * M_ + 2 * WAVES);

    const int b   = blockIdx.x / BPB;
    const int blk = blockIdx.x % BPB;
    const int n0  = blk * RPB;
    const int tid = threadIdx.x;
    const bool designated = (blk == 0);

    // ---- staging: scaled sorted points + per-column factors ----
    for (int m = tid; m < M_; m += THREADS) {
        const float4 q = xyz2s[b * M_ + m];
        float g = 0.f, rn = 1.f;
        if (has_p2) {
            const float rr = rRp[b * M_ + m];
            const float sv = ssp_g[b * M_ + m];
            const float ratio = fminf(rr / (sv + EPS), 1.f);
            g  = rr * ratio;
            rn = fmaxf(rr - sv * ratio, 0.f);
        }
        sp[m] = make_float4(q.x * ascale, q.y * ascale, q.z * ascale, rn);
        sg[m] = g;
        if (designated) {
            if (has_p1) rRn_g[b * M_ + m] = rn;
            ssz_g[b * M_ + m] = 0.f;
        }
    }
    if (tid < 32) {
        const float2 bb = bounds2[b * 32 + tid];
        bnds[tid] = make_float2(bb.x * ascale, bb.y * ascale);
    }
    __syncthreads();

    const int wave = tid >> 6, lane = tid & 63;
    const int nw = n0 + wave * RPW;

    float xv[RPW], yv[RPW], zv[RPW];
    #pragma unroll
    for (int r = 0; r < RPW; ++r) {
        const float4 q = xyz1s[b * N_ + nw + r];
        xv[r] = q.x * ascale; yv[r] = q.y * ascale; zv[r] = q.z * ascale;
    }

    // ---- per-(wave, k-block) skip masks (wave-uniform) ----
    unsigned mf = 0xffffffffu, mp = 0u;
    if (domask) {
        mf = 0u;
        for (int k = 0; k < 32; ++k) {
            const float2 bb = bnds[k];
            float t2 = 1e30f;
            #pragma unroll
            for (int r = 0; r < RPW; ++r) {
                const float t = fmaxf(fmaxf(bb.x - xv[r], xv[r] - bb.y), 0.f);
                t2 = fminf(t2, t * t);
            }
            if (t2 * 4.f <= 160.f)  mf |= (1u << k);   // phase2 exp may be alive
            else if (t2 <= 160.f)   mp |= (1u << k);   // only p exp alive
        }
    }
    const unsigned alive = mf | mp;

    float accd[RPW], accc[RPW], p[RPW];
    #pragma unroll
    for (int r = 0; r < RPW; ++r) { accd[r] = 0.f; accc[r] = 0.f; p[r] = 0.f; }

    // ---- fused sweep ----
    if (has_p2 && has_p1 && domask) {
        if (mf == 0xffffffffu) {
            // DENSE fast path (s>=5 typically): prefetch-pipelined, unrolled
            float4 c = sp[lane];
            float  g = sg[lane];
            #pragma unroll
            for (int k = 0; k < 32; ++k) {
                const int kn = (((k + 1) & 31) << 6) + lane;
                const float4 cN = sp[kn];
                const float  gN = sg[kn];
                #pragma unroll
                for (int r = 0; r < RPW; ++r) {
                    const float dx = xv[r]-c.x, dy = yv[r]-c.y, dz = zv[r]-c.z;
                    const float s2 = dx*dx + dy*dy + dz*dz;
                    const float ec = __builtin_amdgcn_exp2f(-s2);
                    const float e  = __builtin_amdgcn_exp2f(-4.f * s2) * g;
                    accd[r] += e;
                    accc[r] += e * __builtin_amdgcn_sqrtf(s2);
                    p[r] += ec * c.w;
                }
                c = cN; g = gN;
            }
        } else {
            // masked path (early steps)
            for (int k = 0; k < 32; ++k) {
                if (!((alive >> k) & 1u)) continue;
                const int kk = (k << 6) + lane;
                const float4 c = sp[kk];
                if ((mf >> k) & 1u) {
                    const float g = sg[kk];
                    #pragma unroll
                    for (int r = 0; r < RPW; ++r) {
                        const float dx = xv[r]-c.x, dy = yv[r]-c.y, dz = zv[r]-c.z;
                        const float s2 = dx*dx + dy*dy + dz*dz;
                        const float ec = __builtin_amdgcn_exp2f(-s2);
                        const float e  = __builtin_amdgcn_exp2f(-4.f * s2) * g;
                        accd[r] += e;
                        accc[r] += e * __builtin_amdgcn_sqrtf(s2);
                        p[r] += ec * c.w;
                    }
                } else {
                    #pragma unroll
                    for (int r = 0; r < RPW; ++r) {
                        const float dx = xv[r]-c.x, dy = yv[r]-c.y, dz = zv[r]-c.z;
                        const float s2 = dx*dx + dy*dy + dz*dz;
                        p[r] += __builtin_amdgcn_exp2f(-s2) * c.w;
                    }
                }
            }
        }
    } else if (!has_p2) {
        // s=0: p-only, heavily masked
        for (int k = 0; k < 32; ++k) {
            if (!((alive >> k) & 1u)) continue;
            const int kk = (k << 6) + lane;
            const float4 c = sp[kk];
            #pragma unroll
            for (int r = 0; r < RPW; ++r) {
                const float dx = xv[r]-c.x, dy = yv[r]-c.y, dz = zv[r]-c.z;
                const float s2 = dx*dx + dy*dy + dz*dz;
                p[r] += __builtin_amdgcn_exp2f(-s2) * c.w;
            }
        }
    } else if (has_p1) {
        // s=9: always dense -> prefetch-pipelined
        float4 c = sp[lane];
        float  g = sg[lane];
        #pragma unroll
        for (int k = 0; k < 32; ++k) {
            const int kn = (((k + 1) & 31) << 6) + lane;
            const float4 cN = sp[kn];
            const float  gN = sg[kn];
            #pragma unroll
            for (int r = 0; r < RPW; ++r) {
                const float dx = xv[r]-c.x, dy = yv[r]-c.y, dz = zv[r]-c.z;
                const float s2 = dx*dx + dy*dy + dz*dz;
                const float e  = __builtin_amdgcn_exp2f(-s2) * g;
                accd[r] += e;
                accc[r] += e * __builtin_amdgcn_sqrtf(s2);
                p[r] += c.w;
            }
            c = cN; g = gN;
        }
    } else {
        // s=10: dense, no exp (e = g exactly; ascale = 1)
        float4 c = sp[lane];
        float  g = sg[lane];
        #pragma unroll
        for (int k = 0; k < 32; ++k) {
            const int kn = (((k + 1) & 31) << 6) + lane;
            const float4 cN = sp[kn];
            const float  gN = sg[kn];
            #pragma unroll
            for (int r = 0; r < RPW; ++r) {
                const float dx = xv[r]-c.x, dy = yv[r]-c.y, dz = zv[r]-c.z;
                const float s2 = dx*dx + dy*dy + dz*dz;
                accd[r] += g;
                accc[r] += g * __builtin_amdgcn_sqrtf(s2);
            }
            c = cN; g = gN;
        }
    }

    // ---- wave reductions (rows are wave-private) ----
    if (has_p2) {
        #pragma unroll
        for (int r = 0; r < RPW; ++r) {
            #pragma unroll
            for (int off = 32; off >= 1; off >>= 1) {
                accd[r] += __shfl_xor(accd[r], off, 64);
                accc[r] += __shfl_xor(accc[r], off, 64);
            }
        }
    }
    if (has_p1) {
        #pragma unroll
        for (int r = 0; r < RPW; ++r) {
            #pragma unroll
            for (int off = 32; off >= 1; off >>= 1)
                p[r] += __shfl_xor(p[r], off, 64);
        }
    }

    float rl_new[RPW];
    float cw = 0.f;
    if (has_p2) {
        #pragma unroll
        for (int r = 0; r < RPW; ++r) {
            const int idx = b * N_ + nw + r;
            const float fo = fb[idx];               // f(s-1), broadcast load
            const float rl = rLb[idx];
            rl_new[r] = fmaxf(rl - fo * accd[r], 0.f);
            cw += fo * accc[r];
        }
    } else {
        #pragma unroll
        for (int r = 0; r < RPW; ++r) rl_new[r] = 1.f;
    }
    if (lane == 0) wcost[wave] = cw * inva;  // fold 1/a: sqrt(s2) = a*sqrt(d2)

    // ---- phase1 colsums ----
    if (has_p1) {
        float fn[RPW];
        #pragma unroll
        for (int r = 0; r < RPW; ++r)
            fn[r] = rl_new[r] / (p[r] + EPS);
        if (lane == 0) {
            #pragma unroll
            for (int r = 0; r < RPW; ++r) {
                const int idx = b * N_ + nw + r;
                fb[idx]  = fn[r];
                rLb[idx] = rl_new[r];
            }
        }
        if (!lcz) {
            float ssp[32];
            if (alive == 0xffffffffu) {
                // DENSE fast path: prefetch-pipelined colsum
                float4 c = sp[lane];
                #pragma unroll
                for (int k = 0; k < 32; ++k) {
                    const float4 cN = sp[(((k + 1) & 31) << 6) + lane];
                    float acc = 0.f;
                    #pragma unroll
                    for (int r = 0; r < RPW; ++r) {
                        const float dx = xv[r]-c.x, dy = yv[r]-c.y, dz = zv[r]-c.z;
                        const float s2 = dx*dx + dy*dy + dz*dz;
                        acc += __builtin_amdgcn_exp2f(-s2) * fn[r];
                    }
                    ssp[k] = acc * c.w;
                    c = cN;
                }
            } else {
                for (int k = 0; k < 32; ++k) {
                    float sv = 0.f;
                    if ((alive >> k) & 1u) {
                        const int kk = (k << 6) + lane;
                        const float4 c = sp[kk];
                        float acc = 0.f;
                        #pragma unroll
                        for (int r = 0; r < RPW; ++r) {
                            const float dx = xv[r]-c.x, dy = yv[r]-c.y, dz = zv[r]-c.z;
                            const float s2 = dx*dx + dy*dy + dz*dz;
                            acc += __builtin_amdgcn_exp2f(-s2) * fn[r];
                        }
                        sv = acc * c.w;
                    }
                    ssp[k] = sv;
                }
            }
            __syncthreads();   // all sp/sg reads done -> ssl overlay safe
            #pragma unroll
            for (int k = 0; k < 32; ++k)
                ssl[wave * M_ + (k << 6) + lane] = ssp[k];
            __syncthreads();
            if (tid == 0 && has_p2) {
                float t = 0.f;
                #pragma unroll
                for (int w = 0; w < WAVES; ++w) t += wcost[w];
                atomicAdd(&out[b], t);
            }
            for (int m = tid; m < M_; m += THREADS) {
                const float sval = ssl[m]        + ssl[M_ + m]   + ssl[2*M_ + m]
                                 + ssl[3*M_ + m] + ssl[4*M_ + m] + ssl[5*M_ + m]
                                 + ssl[6*M_ + m] + ssl[7*M_ + m];
                if (sval != 0.f) atomicAdd(&ssc_g[b * M_ + m], sval);
            }
        } else {
            // s=9: l2c == 0 -> ec == 1 -> ss(m) = rn(m) * sum_block(fn)
            if (lane == 0) sfn_l[wave] = fn[0] + fn[1] + fn[2] + fn[3];
            __syncthreads();
            if (tid == 0 && has_p2) {
                float t = 0.f;
                #pragma unroll
                for (int w = 0; w < WAVES; ++w) t += wcost[w];
                atomicAdd(&out[b], t);
            }
            float tot = 0.f;
            #pragma unroll
            for (int w = 0; w < WAVES; ++w) tot += sfn_l[w];
            for (int m = tid; m < M_; m += THREADS) {
                const float v = sp[m].w * tot;
                if (v != 0.f) atomicAdd(&ssc_g[b * M_ + m], v);
            }
        }
    } else {
        __syncthreads();   // wcost visible
        if (tid == 0) {
            float t = 0.f;
            #pragma unroll
            for (int w = 0; w < WAVES; ++w) t += wcost[w];
            atomicAdd(&out[b], t);
        }
    }
}

extern "C" void kernel_launch(void* const* d_in, const int* in_sizes, int n_in,
                              void* d_out, int out_size, void* d_ws, size_t ws_size,
                              hipStream_t stream) {
    const float* xyz1 = (const float*)d_in[0];
    const float* xyz2 = (const float*)d_in[1];
    float* out = (float*)d_out;
    float* ws = (float*)d_ws;
    const int SZ = B_ * N_;          // == B_*M_ == 16384
    float* rL  = ws;
    float* fb  = ws + SZ;
    float* rRb[2] = { ws + 2*SZ, ws + 3*SZ };
    float* ssb[3] = { ws + 4*SZ, ws + 5*SZ, ws + 6*SZ };
    float2* bounds2 = (float2*)(ws + 7*SZ);            // 8*32 float2 = 512 floats
    float4* xyz1s   = (float4*)(ws + 7*SZ + 512);      // 16B-aligned (offset 460800B)
    float4* xyz2s   = xyz1s + (size_t)B_ * N_;
    // workspace footprint: 7*SZ + 512 + 2*16384*4 floats ≈ 985 KB

    init_kernel<<<(SZ + 255) / 256, 256, 0, stream>>>(rL, fb, ssb[0], out);
    sort_kernel<<<2 * B_, 1024, 0, stream>>>(xyz1, xyz2, xyz1s, xyz2s, bounds2);

    constexpr float LOG2E = 1.4426950408889634f;
    static const float levels[10] = {
        -16384.f, -4096.f, -1024.f, -256.f, -64.f,
        -16.f, -4.f, -1.f, -0.25f, 0.f
    };
    // kernel s (s=0..10): phase2 of step s-1 (if s>0) + phase1 of step s (if s<10)
    for (int s = 0; s <= 10; ++s) {
        const int has_p2 = (s > 0);
        const int has_p1 = (s < 10);
        const int domask = (s <= 8);             // masks valid (level finite)
        const int lcz    = (s == 9);             // l2c == 0
        const float lvl  = (s <= 8) ? levels[s] : levels[8];
        const float ascale = (s == 10) ? 1.f : sqrtf(-(lvl * LOG2E));
        const float inva   = 1.f / ascale;
        fused_step<<<GRID, THREADS, 0, stream>>>(
            xyz1s, xyz2s, bounds2, rL, fb,
            rRb[(s + 1) & 1],      // rR(s-1)   (s>=1; unused at s=0)
            rRb[s & 1],            // rR(s) out
            ssb[(s + 2) % 3],      // ss(s-1)   (s>=1; unused at s=0)
            ssb[s % 3],            // ss(s) accumulate (pre-zeroed by kernel s-1 / init)
            ssb[(s + 1) % 3],      // ss(s+1) zeroed for next kernel
            out, ascale, inva, has_p2, has_p1, domask, lcz);
    }
}

// Round 10
// 372.827 us; speedup vs baseline: 1.1431x; 1.1431x over previous
//
#include <hip/hip_runtime.h>
#include <math.h>

#define EPS 1e-9f

constexpr int B_ = 8, N_ = 2048, M_ = 2048;
constexpr int THREADS = 512;               // 8 waves/block
constexpr int WAVES = 8;
constexpr int RPW = 4;                     // rows per wave (wave-uniform rows!)
constexpr int RPB = WAVES * RPW;           // 32 rows per block
constexpr int BPB = N_ / RPB;              // 64 blocks per batch
constexpr int GRID = B_ * BPB;             // 512 blocks

__global__ __launch_bounds__(256) void init_kernel(float* rL, float* fb,
                                                   float* ss0, float* out) {
    int i = blockIdx.x * blockDim.x + threadIdx.x;
    if (i < B_ * N_) { rL[i] = 1.f; fb[i] = 0.f; ss0[i] = 0.f; }
    if (i < B_) out[i] = 0.f;
}

// Merged sort (round-8): key+index bitonic, wave-local phases barrier-free,
// 16 blocks (both arrays concurrent).
__global__ __launch_bounds__(1024) void sort_kernel(
        const float* __restrict__ xyz1, const float* __restrict__ xyz2,
        float4* __restrict__ out1, float4* __restrict__ out2,
        float2* __restrict__ bounds) {
    __shared__ float kx[2048];
    __shared__ int   ki[2048];
    const int bb = blockIdx.x;
    const bool isB = (bb >= B_);
    const int b = isB ? bb - B_ : bb;
    const float* __restrict__ src = isB ? xyz2 : xyz1;
    float4* __restrict__ dst = isB ? out2 : out1;
    const int t = threadIdx.x;

    for (int i = t; i < 2048; i += 1024) {
        kx[i] = src[((size_t)b * 2048 + i) * 3];
        ki[i] = i;
    }
    __syncthreads();

    bool prev_cross = false;
    for (int ksz = 2; ksz <= 2048; ksz <<= 1) {
        for (int j = ksz >> 1; j >= 1; j >>= 1) {
            const bool cross = (j >= 128);
            if (cross || prev_cross) __syncthreads();
            else __builtin_amdgcn_wave_barrier();
            const int i  = t + (t & ~(j - 1));
            const int pr = i + j;
            const bool up = ((i & ksz) == 0);
            const float ax = kx[i], bx = kx[pr];
            if ((ax > bx) == up) {
                const int ai = ki[i], bi = ki[pr];
                kx[i] = bx; kx[pr] = ax;
                ki[i] = bi; ki[pr] = ai;
            }
            prev_cross = cross;
        }
    }
    __syncthreads();

    for (int i = t; i < 2048; i += 1024) {
        const float* q = src + ((size_t)b * 2048 + ki[i]) * 3;
        dst[(size_t)b * 2048 + i] = make_float4(q[0], q[1], q[2], 0.f);
    }
    if (isB && t < 32)
        bounds[b * 32 + t] = make_float2(kx[t * 64], kx[t * 64 + 63]);
}

// KERNEL A — round-8 fused_step VERBATIM (round-9 prefetch reverted).
// Used for s in {0,1,2,3,4,9,10}.
__global__ __launch_bounds__(THREADS, 2) void fused_step(
        const float4* __restrict__ xyz1s, const float4* __restrict__ xyz2s,
        const float2* __restrict__ bounds2,
        float* __restrict__ rLb, float* __restrict__ fb,
        const float* __restrict__ rRp,   // rR(s-1) in   (unused if !has_p2)
        float* __restrict__ rRn_g,       // rR(s)  out   (designated block)
        const float* __restrict__ ssp_g, // ss(s-1) in   (unused if !has_p2)
        float* __restrict__ ssc_g,       // ss(s) atomic accumulate (pre-zeroed)
        float* __restrict__ ssz_g,       // ss(s+1) zeroed here for next kernel
        float* __restrict__ out,
        float ascale, float inva, int has_p2, int has_p1, int domask, int lcz)
{
    __shared__ __align__(16) float raw[8 * M_ + 2 * WAVES + 64];
    float4* sp    = (float4*)raw;
    float*  sg    = raw + 4 * M_;
    float*  ssl   = raw;
    float*  wcost = raw + 8 * M_;
    float*  sfn_l = raw + 8 * M_ + WAVES;
    float2* bnds  = (float2*)(raw + 8 * M_ + 2 * WAVES);

    const int b   = blockIdx.x / BPB;
    const int blk = blockIdx.x % BPB;
    const int n0  = blk * RPB;
    const int tid = threadIdx.x;
    const bool designated = (blk == 0);

    for (int m = tid; m < M_; m += THREADS) {
        const float4 q = xyz2s[b * M_ + m];
        float g = 0.f, rn = 1.f;
        if (has_p2) {
            const float rr = rRp[b * M_ + m];
            const float sv = ssp_g[b * M_ + m];
            const float ratio = fminf(rr / (sv + EPS), 1.f);
            g  = rr * ratio;
            rn = fmaxf(rr - sv * ratio, 0.f);
        }
        sp[m] = make_float4(q.x * ascale, q.y * ascale, q.z * ascale, rn);
        sg[m] = g;
        if (designated) {
            if (has_p1) rRn_g[b * M_ + m] = rn;
            ssz_g[b * M_ + m] = 0.f;
        }
    }
    if (tid < 32) {
        const float2 bb = bounds2[b * 32 + tid];
        bnds[tid] = make_float2(bb.x * ascale, bb.y * ascale);
    }
    __syncthreads();

    const int wave = tid >> 6, lane = tid & 63;
    const int nw = n0 + wave * RPW;

    float xv[RPW], yv[RPW], zv[RPW];
    #pragma unroll
    for (int r = 0; r < RPW; ++r) {
        const float4 q = xyz1s[b * N_ + nw + r];
        xv[r] = q.x * ascale; yv[r] = q.y * ascale; zv[r] = q.z * ascale;
    }

    unsigned mf = 0xffffffffu, mp = 0u;
    if (domask) {
        mf = 0u;
        for (int k = 0; k < 32; ++k) {
            const float2 bb = bnds[k];
            float t2 = 1e30f;
            #pragma unroll
            for (int r = 0; r < RPW; ++r) {
                const float t = fmaxf(fmaxf(bb.x - xv[r], xv[r] - bb.y), 0.f);
                t2 = fminf(t2, t * t);
            }
            if (t2 * 4.f <= 160.f)  mf |= (1u << k);
            else if (t2 <= 160.f)   mp |= (1u << k);
        }
    }
    const unsigned alive = mf | mp;

    float accd[RPW], accc[RPW], p[RPW];
    #pragma unroll
    for (int r = 0; r < RPW; ++r) { accd[r] = 0.f; accc[r] = 0.f; p[r] = 0.f; }

    if (has_p2 && has_p1 && domask) {
        for (int k = 0; k < 32; ++k) {
            if (!((alive >> k) & 1u)) continue;
            const int kk = (k << 6) + lane;
            const float4 c = sp[kk];
            if ((mf >> k) & 1u) {
                const float g = sg[kk];
                #pragma unroll
                for (int r = 0; r < RPW; ++r) {
                    const float dx = xv[r]-c.x, dy = yv[r]-c.y, dz = zv[r]-c.z;
                    const float s2 = dx*dx + dy*dy + dz*dz;
                    const float ec = __builtin_amdgcn_exp2f(-s2);
                    const float e  = __builtin_amdgcn_exp2f(-4.f * s2) * g;
                    accd[r] += e;
                    accc[r] += e * __builtin_amdgcn_sqrtf(s2);
                    p[r] += ec * c.w;
                }
            } else {
                #pragma unroll
                for (int r = 0; r < RPW; ++r) {
                    const float dx = xv[r]-c.x, dy = yv[r]-c.y, dz = zv[r]-c.z;
                    const float s2 = dx*dx + dy*dy + dz*dz;
                    p[r] += __builtin_amdgcn_exp2f(-s2) * c.w;
                }
            }
        }
    } else if (!has_p2) {
        for (int k = 0; k < 32; ++k) {
            if (!((alive >> k) & 1u)) continue;
            const int kk = (k << 6) + lane;
            const float4 c = sp[kk];
            #pragma unroll
            for (int r = 0; r < RPW; ++r) {
                const float dx = xv[r]-c.x, dy = yv[r]-c.y, dz = zv[r]-c.z;
                const float s2 = dx*dx + dy*dy + dz*dz;
                p[r] += __builtin_amdgcn_exp2f(-s2) * c.w;
            }
        }
    } else if (has_p1) {
        // s=9
        for (int k = 0; k < 32; ++k) {
            const int kk = (k << 6) + lane;
            const float4 c = sp[kk];
            const float  g = sg[kk];
            #pragma unroll
            for (int r = 0; r < RPW; ++r) {
                const float dx = xv[r]-c.x, dy = yv[r]-c.y, dz = zv[r]-c.z;
                const float s2 = dx*dx + dy*dy + dz*dz;
                const float e  = __builtin_amdgcn_exp2f(-s2) * g;
                accd[r] += e;
                accc[r] += e * __builtin_amdgcn_sqrtf(s2);
                p[r] += c.w;
            }
        }
    } else {
        // s=10
        for (int k = 0; k < 32; ++k) {
            const int kk = (k << 6) + lane;
            const float4 c = sp[kk];
            const float  g = sg[kk];
            #pragma unroll
            for (int r = 0; r < RPW; ++r) {
                const float dx = xv[r]-c.x, dy = yv[r]-c.y, dz = zv[r]-c.z;
                const float s2 = dx*dx + dy*dy + dz*dz;
                accd[r] += g;
                accc[r] += g * __builtin_amdgcn_sqrtf(s2);
            }
        }
    }

    if (has_p2) {
        #pragma unroll
        for (int r = 0; r < RPW; ++r) {
            #pragma unroll
            for (int off = 32; off >= 1; off >>= 1) {
                accd[r] += __shfl_xor(accd[r], off, 64);
                accc[r] += __shfl_xor(accc[r], off, 64);
            }
        }
    }
    if (has_p1) {
        #pragma unroll
        for (int r = 0; r < RPW; ++r) {
            #pragma unroll
            for (int off = 32; off >= 1; off >>= 1)
                p[r] += __shfl_xor(p[r], off, 64);
        }
    }

    float rl_new[RPW];
    float cw = 0.f;
    if (has_p2) {
        #pragma unroll
        for (int r = 0; r < RPW; ++r) {
            const int idx = b * N_ + nw + r;
            const float fo = fb[idx];
            const float rl = rLb[idx];
            rl_new[r] = fmaxf(rl - fo * accd[r], 0.f);
            cw += fo * accc[r];
        }
    } else {
        #pragma unroll
        for (int r = 0; r < RPW; ++r) rl_new[r] = 1.f;
    }
    if (lane == 0) wcost[wave] = cw * inva;

    if (has_p1) {
        float fn[RPW];
        #pragma unroll
        for (int r = 0; r < RPW; ++r)
            fn[r] = rl_new[r] / (p[r] + EPS);
        if (lane == 0) {
            #pragma unroll
            for (int r = 0; r < RPW; ++r) {
                const int idx = b * N_ + nw + r;
                fb[idx]  = fn[r];
                rLb[idx] = rl_new[r];
            }
        }
        if (!lcz) {
            float ssp[32];
            for (int k = 0; k < 32; ++k) {
                float sv = 0.f;
                if ((alive >> k) & 1u) {
                    const int kk = (k << 6) + lane;
                    const float4 c = sp[kk];
                    float acc = 0.f;
                    #pragma unroll
                    for (int r = 0; r < RPW; ++r) {
                        const float dx = xv[r]-c.x, dy = yv[r]-c.y, dz = zv[r]-c.z;
                        const float s2 = dx*dx + dy*dy + dz*dz;
                        acc += __builtin_amdgcn_exp2f(-s2) * fn[r];
                    }
                    sv = acc * c.w;
                }
                ssp[k] = sv;
            }
            __syncthreads();
            #pragma unroll
            for (int k = 0; k < 32; ++k)
                ssl[wave * M_ + (k << 6) + lane] = ssp[k];
            __syncthreads();
            if (tid == 0 && has_p2) {
                float t = 0.f;
                #pragma unroll
                for (int w = 0; w < WAVES; ++w) t += wcost[w];
                atomicAdd(&out[b], t);
            }
            for (int m = tid; m < M_; m += THREADS) {
                const float sval = ssl[m]        + ssl[M_ + m]   + ssl[2*M_ + m]
                                 + ssl[3*M_ + m] + ssl[4*M_ + m] + ssl[5*M_ + m]
                                 + ssl[6*M_ + m] + ssl[7*M_ + m];
                if (sval != 0.f) atomicAdd(&ssc_g[b * M_ + m], sval);
            }
        } else {
            if (lane == 0) sfn_l[wave] = fn[0] + fn[1] + fn[2] + fn[3];
            __syncthreads();
            if (tid == 0 && has_p2) {
                float t = 0.f;
                #pragma unroll
                for (int w = 0; w < WAVES; ++w) t += wcost[w];
                atomicAdd(&out[b], t);
            }
            float tot = 0.f;
            #pragma unroll
            for (int w = 0; w < WAVES; ++w) tot += sfn_l[w];
            for (int m = tid; m < M_; m += THREADS) {
                const float v = sp[m].w * tot;
                if (v != 0.f) atomicAdd(&ssc_g[b * M_ + m], v);
            }
        }
    } else {
        __syncthreads();
        if (tid == 0) {
            float t = 0.f;
            #pragma unroll
            for (int w = 0; w < WAVES; ++w) t += wcost[w];
            atomicAdd(&out[b], t);
        }
    }
}

// KERNEL B — s in 5..8 only (has_p2=has_p1=domask=1, lcz=0).
// ec-CACHE: the colsum's exp2(-s2) is bit-identical to the main sweep's ec,
// so cache it in ec_c[32][RPW] (128 VGPR, statically indexed via full unroll)
// and collapse colsum from 7 VALU + 1 trans per pair to ~1.25 VALU.
// Theory: dense sweep is VALU-ISSUE-bound (masked speedups work-proportional;
// e^4 trick (-trans +VALU) hurt; prefetch (+VALU) hurt; occupancy 2..8 w/SIMD
// flat). -25% total issue predicted -> ~31us. VGPR ~190 -> 2 waves/SIMD,
// 1 block/CU: acceptable (round-0: 2/SIMD == 4/SIMD at same code).
// ssl is a SEPARATE 64KB region (no overlay, LDS ~107KB): deletes ssp[32]
// and one barrier. All expression orders identical to kernel A -> bit-exact.
__global__ __launch_bounds__(THREADS, 2) void fused_dense(
        const float4* __restrict__ xyz1s, const float4* __restrict__ xyz2s,
        const float2* __restrict__ bounds2,
        float* __restrict__ rLb, float* __restrict__ fb,
        const float* __restrict__ rRp,
        float* __restrict__ rRn_g,
        const float* __restrict__ ssp_g,
        float* __restrict__ ssc_g,
        float* __restrict__ ssz_g,
        float* __restrict__ out,
        float ascale, float inva)
{
    // sp 32KB | sg 8KB | ssl 64KB (separate!) | wcost | bnds
    __shared__ __align__(16) float raw[13 * M_ + WAVES + 64];
    float4* sp    = (float4*)raw;
    float*  sg    = raw + 4 * M_;
    float*  ssl   = raw + 5 * M_;
    float*  wcost = raw + 13 * M_;
    float2* bnds  = (float2*)(raw + 13 * M_ + WAVES);

    const int b   = blockIdx.x / BPB;
    const int blk = blockIdx.x % BPB;
    const int n0  = blk * RPB;
    const int tid = threadIdx.x;
    const bool designated = (blk == 0);

    for (int m = tid; m < M_; m += THREADS) {
        const float4 q = xyz2s[b * M_ + m];
        const float rr = rRp[b * M_ + m];
        const float sv = ssp_g[b * M_ + m];
        const float ratio = fminf(rr / (sv + EPS), 1.f);
        const float g  = rr * ratio;
        const float rn = fmaxf(rr - sv * ratio, 0.f);
        sp[m] = make_float4(q.x * ascale, q.y * ascale, q.z * ascale, rn);
        sg[m] = g;
        if (designated) {
            rRn_g[b * M_ + m] = rn;
            ssz_g[b * M_ + m] = 0.f;
        }
    }
    if (tid < 32) {
        const float2 bb = bounds2[b * 32 + tid];
        bnds[tid] = make_float2(bb.x * ascale, bb.y * ascale);
    }
    __syncthreads();

    const int wave = tid >> 6, lane = tid & 63;
    const int nw = n0 + wave * RPW;

    float xv[RPW], yv[RPW], zv[RPW];
    #pragma unroll
    for (int r = 0; r < RPW; ++r) {
        const float4 q = xyz1s[b * N_ + nw + r];
        xv[r] = q.x * ascale; yv[r] = q.y * ascale; zv[r] = q.z * ascale;
    }

    unsigned mf = 0u, mp = 0u;
    for (int k = 0; k < 32; ++k) {
        const float2 bb = bnds[k];
        float t2 = 1e30f;
        #pragma unroll
        for (int r = 0; r < RPW; ++r) {
            const float t = fmaxf(fmaxf(bb.x - xv[r], xv[r] - bb.y), 0.f);
            t2 = fminf(t2, t * t);
        }
        if (t2 * 4.f <= 160.f)  mf |= (1u << k);
        else if (t2 <= 160.f)   mp |= (1u << k);
    }
    const unsigned alive = mf | mp;
    const bool cached = (mf == 0xffffffffu);

    float accd[RPW], accc[RPW], p[RPW];
    #pragma unroll
    for (int r = 0; r < RPW; ++r) { accd[r] = 0.f; accc[r] = 0.f; p[r] = 0.f; }

    float ec_c[32][RPW];   // static indexing only (full unroll) — stays in VGPRs

    if (cached) {
        #pragma unroll
        for (int k = 0; k < 32; ++k) {
            const int kk = (k << 6) + lane;
            const float4 c = sp[kk];
            const float  g = sg[kk];
            #pragma unroll
            for (int r = 0; r < RPW; ++r) {
                const float dx = xv[r]-c.x, dy = yv[r]-c.y, dz = zv[r]-c.z;
                const float s2 = dx*dx + dy*dy + dz*dz;
                const float ec = __builtin_amdgcn_exp2f(-s2);
                ec_c[k][r] = ec;
                const float e  = __builtin_amdgcn_exp2f(-4.f * s2) * g;
                accd[r] += e;
                accc[r] += e * __builtin_amdgcn_sqrtf(s2);
                p[r] += ec * c.w;
            }
        }
    } else {
        // edge waves (partial mask): kernel-A masked path, ec not cached
        for (int k = 0; k < 32; ++k) {
            if (!((alive >> k) & 1u)) continue;
            const int kk = (k << 6) + lane;
            const float4 c = sp[kk];
            if ((mf >> k) & 1u) {
                const float g = sg[kk];
                #pragma unroll
                for (int r = 0; r < RPW; ++r) {
                    const float dx = xv[r]-c.x, dy = yv[r]-c.y, dz = zv[r]-c.z;
                    const float s2 = dx*dx + dy*dy + dz*dz;
                    const float ec = __builtin_amdgcn_exp2f(-s2);
                    const float e  = __builtin_amdgcn_exp2f(-4.f * s2) * g;
                    accd[r] += e;
                    accc[r] += e * __builtin_amdgcn_sqrtf(s2);
                    p[r] += ec * c.w;
                }
            } else {
                #pragma unroll
                for (int r = 0; r < RPW; ++r) {
                    const float dx = xv[r]-c.x, dy = yv[r]-c.y, dz = zv[r]-c.z;
                    const float s2 = dx*dx + dy*dy + dz*dz;
                    p[r] += __builtin_amdgcn_exp2f(-s2) * c.w;
                }
            }
        }
    }

    #pragma unroll
    for (int r = 0; r < RPW; ++r) {
        #pragma unroll
        for (int off = 32; off >= 1; off >>= 1) {
            accd[r] += __shfl_xor(accd[r], off, 64);
            accc[r] += __shfl_xor(accc[r], off, 64);
        }
    }
    #pragma unroll
    for (int r = 0; r < RPW; ++r) {
        #pragma unroll
        for (int off = 32; off >= 1; off >>= 1)
            p[r] += __shfl_xor(p[r], off, 64);
    }

    float rl_new[RPW];
    float cw = 0.f;
    #pragma unroll
    for (int r = 0; r < RPW; ++r) {
        const int idx = b * N_ + nw + r;
        const float fo = fb[idx];
        const float rl = rLb[idx];
        rl_new[r] = fmaxf(rl - fo * accd[r], 0.f);
        cw += fo * accc[r];
    }
    if (lane == 0) wcost[wave] = cw * inva;

    float fn[RPW];
    #pragma unroll
    for (int r = 0; r < RPW; ++r)
        fn[r] = rl_new[r] / (p[r] + EPS);
    if (lane == 0) {
        #pragma unroll
        for (int r = 0; r < RPW; ++r) {
            const int idx = b * N_ + nw + r;
            fb[idx]  = fn[r];
            rLb[idx] = rl_new[r];
        }
    }

    // ---- colsum: cached = 4 FMA + 1 mul per k (no exp2, no d2) ----
    if (cached) {
        #pragma unroll
        for (int k = 0; k < 32; ++k) {
            const int kk = (k << 6) + lane;
            float acc = 0.f;
            #pragma unroll
            for (int r = 0; r < RPW; ++r)
                acc += ec_c[k][r] * fn[r];
            ssl[wave * M_ + kk] = acc * sp[kk].w;
        }
    } else {
        for (int k = 0; k < 32; ++k) {
            const int kk = (k << 6) + lane;
            float sv = 0.f;
            if ((alive >> k) & 1u) {
                const float4 c = sp[kk];
                float acc = 0.f;
                #pragma unroll
                for (int r = 0; r < RPW; ++r) {
                    const float dx = xv[r]-c.x, dy = yv[r]-c.y, dz = zv[r]-c.z;
                    const float s2 = dx*dx + dy*dy + dz*dz;
                    acc += __builtin_amdgcn_exp2f(-s2) * fn[r];
                }
                sv = acc * c.w;
            }
            ssl[wave * M_ + kk] = sv;
        }
    }
    __syncthreads();   // ssl complete; wcost visible
    if (tid == 0) {
        float t = 0.f;
        #pragma unroll
        for (int w = 0; w < WAVES; ++w) t += wcost[w];
        atomicAdd(&out[b], t);
    }
    for (int m = tid; m < M_; m += THREADS) {
        const float sval = ssl[m]        + ssl[M_ + m]   + ssl[2*M_ + m]
                         + ssl[3*M_ + m] + ssl[4*M_ + m] + ssl[5*M_ + m]
                         + ssl[6*M_ + m] + ssl[7*M_ + m];
        if (sval != 0.f) atomicAdd(&ssc_g[b * M_ + m], sval);
    }
}

extern "C" void kernel_launch(void* const* d_in, const int* in_sizes, int n_in,
                              void* d_out, int out_size, void* d_ws, size_t ws_size,
                              hipStream_t stream) {
    const float* xyz1 = (const float*)d_in[0];
    const float* xyz2 = (const float*)d_in[1];
    float* out = (float*)d_out;
    float* ws = (float*)d_ws;
    const int SZ = B_ * N_;          // == B_*M_ == 16384
    float* rL  = ws;
    float* fb  = ws + SZ;
    float* rRb[2] = { ws + 2*SZ, ws + 3*SZ };
    float* ssb[3] = { ws + 4*SZ, ws + 5*SZ, ws + 6*SZ };
    float2* bounds2 = (float2*)(ws + 7*SZ);
    float4* xyz1s   = (float4*)(ws + 7*SZ + 512);
    float4* xyz2s   = xyz1s + (size_t)B_ * N_;

    init_kernel<<<(SZ + 255) / 256, 256, 0, stream>>>(rL, fb, ssb[0], out);
    sort_kernel<<<2 * B_, 1024, 0, stream>>>(xyz1, xyz2, xyz1s, xyz2s, bounds2);

    constexpr float LOG2E = 1.4426950408889634f;
    static const float levels[10] = {
        -16384.f, -4096.f, -1024.f, -256.f, -64.f,
        -16.f, -4.f, -1.f, -0.25f, 0.f
    };
    for (int s = 0; s <= 10; ++s) {
        const int has_p2 = (s > 0);
        const int has_p1 = (s < 10);
        const int domask = (s <= 8);
        const int lcz    = (s == 9);
        const float lvl  = (s <= 8) ? levels[s] : levels[8];
        const float ascale = (s == 10) ? 1.f : sqrtf(-(lvl * LOG2E));
        const float inva   = 1.f / ascale;
        if (s >= 5 && s <= 8) {
            fused_dense<<<GRID, THREADS, 0, stream>>>(
                xyz1s, xyz2s, bounds2, rL, fb,
                rRb[(s + 1) & 1], rRb[s & 1],
                ssb[(s + 2) % 3], ssb[s % 3], ssb[(s + 1) % 3],
                out, ascale, inva);
        } else {
            fused_step<<<GRID, THREADS, 0, stream>>>(
                xyz1s, xyz2s, bounds2, rL, fb,
                rRb[(s + 1) & 1], rRb[s & 1],
                ssb[(s + 2) % 3], ssb[s % 3], ssb[(s + 1) % 3],
                out, ascale, inva, has_p2, has_p1, domask, lcz);
        }
    }
}

// Round 11
// 364.169 us; speedup vs baseline: 1.1702x; 1.0238x over previous
//
#include <hip/hip_runtime.h>
#include <math.h>

#define EPS 1e-9f

constexpr int B_ = 8, N_ = 2048, M_ = 2048;
constexpr int THREADS = 512;               // 8 waves/block
constexpr int WAVES = 8;
constexpr int RPW = 4;                     // rows per wave (wave-uniform rows!)
constexpr int RPB = WAVES * RPW;           // 32 rows per block
constexpr int BPB = N_ / RPB;              // 64 blocks per batch
constexpr int GRID = B_ * BPB;             // 512 blocks = 2/CU

__global__ __launch_bounds__(256) void init_kernel(float* rL, float* fb,
                                                   float* ss0, float* out) {
    int i = blockIdx.x * blockDim.x + threadIdx.x;
    if (i < B_ * N_) { rL[i] = 1.f; fb[i] = 0.f; ss0[i] = 0.f; }
    if (i < B_) out[i] = 0.f;
}

// Merged sort (round-8): key+index bitonic, wave-local phases barrier-free,
// 16 blocks (both arrays concurrent).
__global__ __launch_bounds__(1024) void sort_kernel(
        const float* __restrict__ xyz1, const float* __restrict__ xyz2,
        float4* __restrict__ out1, float4* __restrict__ out2,
        float2* __restrict__ bounds) {
    __shared__ float kx[2048];
    __shared__ int   ki[2048];
    const int bb = blockIdx.x;
    const bool isB = (bb >= B_);
    const int b = isB ? bb - B_ : bb;
    const float* __restrict__ src = isB ? xyz2 : xyz1;
    float4* __restrict__ dst = isB ? out2 : out1;
    const int t = threadIdx.x;

    for (int i = t; i < 2048; i += 1024) {
        kx[i] = src[((size_t)b * 2048 + i) * 3];
        ki[i] = i;
    }
    __syncthreads();

    bool prev_cross = false;
    for (int ksz = 2; ksz <= 2048; ksz <<= 1) {
        for (int j = ksz >> 1; j >= 1; j >>= 1) {
            const bool cross = (j >= 128);
            if (cross || prev_cross) __syncthreads();
            else __builtin_amdgcn_wave_barrier();
            const int i  = t + (t & ~(j - 1));
            const int pr = i + j;
            const bool up = ((i & ksz) == 0);
            const float ax = kx[i], bx = kx[pr];
            if ((ax > bx) == up) {
                const int ai = ki[i], bi = ki[pr];
                kx[i] = bx; kx[pr] = ax;
                ki[i] = bi; ki[pr] = ai;
            }
            prev_cross = cross;
        }
    }
    __syncthreads();

    for (int i = t; i < 2048; i += 1024) {
        const float* q = src + ((size_t)b * 2048 + ki[i]) * 3;
        dst[(size_t)b * 2048 + i] = make_float4(q[0], q[1], q[2], 0.f);
    }
    if (isB && t < 32)
        bounds[b * 32 + t] = make_float2(kx[t * 64], kx[t * 64 + 63]);
}

// Round-8 fused_step + round-11 change: BRANCHLESS UNROLLED dense paths.
// When a wave's mask is all-ones (dense levels), the masked loop's per-k
// branch ('continue') pins each k's ds_reads right before their use -> the
// 8 barrier-synced waves convoy: all stall ~120cy on LDS each k in phase.
// A branchless '#pragma unroll 4' loop lets the compiler batch 4 k's of
// loads ahead of the compute group, amortizing the stall 4x. Same
// expressions, same per-accumulator fp order -> numerics identical.
// (round-9 failed this via explicit float4 rotation copies + modulo
// addressing; round-10 via halved occupancy. This is the clean test:
// occupancy, LDS, layout all unchanged from round-8.)
__global__ __launch_bounds__(THREADS, 2) void fused_step(
        const float4* __restrict__ xyz1s, const float4* __restrict__ xyz2s,
        const float2* __restrict__ bounds2,
        float* __restrict__ rLb, float* __restrict__ fb,
        const float* __restrict__ rRp,   // rR(s-1) in   (unused if !has_p2)
        float* __restrict__ rRn_g,       // rR(s)  out   (designated block)
        const float* __restrict__ ssp_g, // ss(s-1) in   (unused if !has_p2)
        float* __restrict__ ssc_g,       // ss(s) atomic accumulate (pre-zeroed)
        float* __restrict__ ssz_g,       // ss(s+1) zeroed here for next kernel
        float* __restrict__ out,
        float ascale, float inva, int has_p2, int has_p1, int domask, int lcz)
{
    __shared__ __align__(16) float raw[8 * M_ + 2 * WAVES + 64];
    float4* sp    = (float4*)raw;
    float*  sg    = raw + 4 * M_;
    float*  ssl   = raw;
    float*  wcost = raw + 8 * M_;
    float*  sfn_l = raw + 8 * M_ + WAVES;
    float2* bnds  = (float2*)(raw + 8 * M_ + 2 * WAVES);

    const int b   = blockIdx.x / BPB;
    const int blk = blockIdx.x % BPB;
    const int n0  = blk * RPB;
    const int tid = threadIdx.x;
    const bool designated = (blk == 0);

    for (int m = tid; m < M_; m += THREADS) {
        const float4 q = xyz2s[b * M_ + m];
        float g = 0.f, rn = 1.f;
        if (has_p2) {
            const float rr = rRp[b * M_ + m];
            const float sv = ssp_g[b * M_ + m];
            const float ratio = fminf(rr / (sv + EPS), 1.f);
            g  = rr * ratio;
            rn = fmaxf(rr - sv * ratio, 0.f);
        }
        sp[m] = make_float4(q.x * ascale, q.y * ascale, q.z * ascale, rn);
        sg[m] = g;
        if (designated) {
            if (has_p1) rRn_g[b * M_ + m] = rn;
            ssz_g[b * M_ + m] = 0.f;
        }
    }
    if (tid < 32) {
        const float2 bb = bounds2[b * 32 + tid];
        bnds[tid] = make_float2(bb.x * ascale, bb.y * ascale);
    }
    __syncthreads();

    const int wave = tid >> 6, lane = tid & 63;
    const int nw = n0 + wave * RPW;

    float xv[RPW], yv[RPW], zv[RPW];
    #pragma unroll
    for (int r = 0; r < RPW; ++r) {
        const float4 q = xyz1s[b * N_ + nw + r];
        xv[r] = q.x * ascale; yv[r] = q.y * ascale; zv[r] = q.z * ascale;
    }

    unsigned mf = 0xffffffffu, mp = 0u;
    if (domask) {
        mf = 0u;
        for (int k = 0; k < 32; ++k) {
            const float2 bb = bnds[k];
            float t2 = 1e30f;
            #pragma unroll
            for (int r = 0; r < RPW; ++r) {
                const float t = fmaxf(fmaxf(bb.x - xv[r], xv[r] - bb.y), 0.f);
                t2 = fminf(t2, t * t);
            }
            if (t2 * 4.f <= 160.f)  mf |= (1u << k);
            else if (t2 <= 160.f)   mp |= (1u << k);
        }
    }
    const unsigned alive = mf | mp;

    float accd[RPW], accc[RPW], p[RPW];
    #pragma unroll
    for (int r = 0; r < RPW; ++r) { accd[r] = 0.f; accc[r] = 0.f; p[r] = 0.f; }

    if (has_p2 && has_p1 && domask) {
        if (mf == 0xffffffffu) {
            // DENSE branchless path: unroll-4 -> loads batched across k
            #pragma unroll 4
            for (int k = 0; k < 32; ++k) {
                const int kk = (k << 6) + lane;
                const float4 c = sp[kk];
                const float  g = sg[kk];
                #pragma unroll
                for (int r = 0; r < RPW; ++r) {
                    const float dx = xv[r]-c.x, dy = yv[r]-c.y, dz = zv[r]-c.z;
                    const float s2 = dx*dx + dy*dy + dz*dz;
                    const float ec = __builtin_amdgcn_exp2f(-s2);
                    const float e  = __builtin_amdgcn_exp2f(-4.f * s2) * g;
                    accd[r] += e;
                    accc[r] += e * __builtin_amdgcn_sqrtf(s2);
                    p[r] += ec * c.w;
                }
            }
        } else {
            // masked path (early steps)
            for (int k = 0; k < 32; ++k) {
                if (!((alive >> k) & 1u)) continue;
                const int kk = (k << 6) + lane;
                const float4 c = sp[kk];
                if ((mf >> k) & 1u) {
                    const float g = sg[kk];
                    #pragma unroll
                    for (int r = 0; r < RPW; ++r) {
                        const float dx = xv[r]-c.x, dy = yv[r]-c.y, dz = zv[r]-c.z;
                        const float s2 = dx*dx + dy*dy + dz*dz;
                        const float ec = __builtin_amdgcn_exp2f(-s2);
                        const float e  = __builtin_amdgcn_exp2f(-4.f * s2) * g;
                        accd[r] += e;
                        accc[r] += e * __builtin_amdgcn_sqrtf(s2);
                        p[r] += ec * c.w;
                    }
                } else {
                    #pragma unroll
                    for (int r = 0; r < RPW; ++r) {
                        const float dx = xv[r]-c.x, dy = yv[r]-c.y, dz = zv[r]-c.z;
                        const float s2 = dx*dx + dy*dy + dz*dz;
                        p[r] += __builtin_amdgcn_exp2f(-s2) * c.w;
                    }
                }
            }
        }
    } else if (!has_p2) {
        for (int k = 0; k < 32; ++k) {
            if (!((alive >> k) & 1u)) continue;
            const int kk = (k << 6) + lane;
            const float4 c = sp[kk];
            #pragma unroll
            for (int r = 0; r < RPW; ++r) {
                const float dx = xv[r]-c.x, dy = yv[r]-c.y, dz = zv[r]-c.z;
                const float s2 = dx*dx + dy*dy + dz*dz;
                p[r] += __builtin_amdgcn_exp2f(-s2) * c.w;
            }
        }
    } else if (has_p1) {
        // s=9: dense, branchless, unrolled
        #pragma unroll 4
        for (int k = 0; k < 32; ++k) {
            const int kk = (k << 6) + lane;
            const float4 c = sp[kk];
            const float  g = sg[kk];
            #pragma unroll
            for (int r = 0; r < RPW; ++r) {
                const float dx = xv[r]-c.x, dy = yv[r]-c.y, dz = zv[r]-c.z;
                const float s2 = dx*dx + dy*dy + dz*dz;
                const float e  = __builtin_amdgcn_exp2f(-s2) * g;
                accd[r] += e;
                accc[r] += e * __builtin_amdgcn_sqrtf(s2);
                p[r] += c.w;
            }
        }
    } else {
        // s=10: dense, no exp, branchless, unrolled
        #pragma unroll 4
        for (int k = 0; k < 32; ++k) {
            const int kk = (k << 6) + lane;
            const float4 c = sp[kk];
            const float  g = sg[kk];
            #pragma unroll
            for (int r = 0; r < RPW; ++r) {
                const float dx = xv[r]-c.x, dy = yv[r]-c.y, dz = zv[r]-c.z;
                const float s2 = dx*dx + dy*dy + dz*dz;
                accd[r] += g;
                accc[r] += g * __builtin_amdgcn_sqrtf(s2);
            }
        }
    }

    if (has_p2) {
        #pragma unroll
        for (int r = 0; r < RPW; ++r) {
            #pragma unroll
            for (int off = 32; off >= 1; off >>= 1) {
                accd[r] += __shfl_xor(accd[r], off, 64);
                accc[r] += __shfl_xor(accc[r], off, 64);
            }
        }
    }
    if (has_p1) {
        #pragma unroll
        for (int r = 0; r < RPW; ++r) {
            #pragma unroll
            for (int off = 32; off >= 1; off >>= 1)
                p[r] += __shfl_xor(p[r], off, 64);
        }
    }

    float rl_new[RPW];
    float cw = 0.f;
    if (has_p2) {
        #pragma unroll
        for (int r = 0; r < RPW; ++r) {
            const int idx = b * N_ + nw + r;
            const float fo = fb[idx];
            const float rl = rLb[idx];
            rl_new[r] = fmaxf(rl - fo * accd[r], 0.f);
            cw += fo * accc[r];
        }
    } else {
        #pragma unroll
        for (int r = 0; r < RPW; ++r) rl_new[r] = 1.f;
    }
    if (lane == 0) wcost[wave] = cw * inva;

    if (has_p1) {
        float fn[RPW];
        #pragma unroll
        for (int r = 0; r < RPW; ++r)
            fn[r] = rl_new[r] / (p[r] + EPS);
        if (lane == 0) {
            #pragma unroll
            for (int r = 0; r < RPW; ++r) {
                const int idx = b * N_ + nw + r;
                fb[idx]  = fn[r];
                rLb[idx] = rl_new[r];
            }
        }
        if (!lcz) {
            float ssp[32];
            if (alive == 0xffffffffu) {
                // DENSE branchless colsum
                #pragma unroll 4
                for (int k = 0; k < 32; ++k) {
                    const int kk = (k << 6) + lane;
                    const float4 c = sp[kk];
                    float acc = 0.f;
                    #pragma unroll
                    for (int r = 0; r < RPW; ++r) {
                        const float dx = xv[r]-c.x, dy = yv[r]-c.y, dz = zv[r]-c.z;
                        const float s2 = dx*dx + dy*dy + dz*dz;
                        acc += __builtin_amdgcn_exp2f(-s2) * fn[r];
                    }
                    ssp[k] = acc * c.w;
                }
            } else {
                for (int k = 0; k < 32; ++k) {
                    float sv = 0.f;
                    if ((alive >> k) & 1u) {
                        const int kk = (k << 6) + lane;
                        const float4 c = sp[kk];
                        float acc = 0.f;
                        #pragma unroll
                        for (int r = 0; r < RPW; ++r) {
                            const float dx = xv[r]-c.x, dy = yv[r]-c.y, dz = zv[r]-c.z;
                            const float s2 = dx*dx + dy*dy + dz*dz;
                            acc += __builtin_amdgcn_exp2f(-s2) * fn[r];
                        }
                        sv = acc * c.w;
                    }
                    ssp[k] = sv;
                }
            }
            __syncthreads();
            #pragma unroll
            for (int k = 0; k < 32; ++k)
                ssl[wave * M_ + (k << 6) + lane] = ssp[k];
            __syncthreads();
            if (tid == 0 && has_p2) {
                float t = 0.f;
                #pragma unroll
                for (int w = 0; w < WAVES; ++w) t += wcost[w];
                atomicAdd(&out[b], t);
            }
            for (int m = tid; m < M_; m += THREADS) {
                const float sval = ssl[m]        + ssl[M_ + m]   + ssl[2*M_ + m]
                                 + ssl[3*M_ + m] + ssl[4*M_ + m] + ssl[5*M_ + m]
                                 + ssl[6*M_ + m] + ssl[7*M_ + m];
                if (sval != 0.f) atomicAdd(&ssc_g[b * M_ + m], sval);
            }
        } else {
            if (lane == 0) sfn_l[wave] = fn[0] + fn[1] + fn[2] + fn[3];
            __syncthreads();
            if (tid == 0 && has_p2) {
                float t = 0.f;
                #pragma unroll
                for (int w = 0; w < WAVES; ++w) t += wcost[w];
                atomicAdd(&out[b], t);
            }
            float tot = 0.f;
            #pragma unroll
            for (int w = 0; w < WAVES; ++w) tot += sfn_l[w];
            for (int m = tid; m < M_; m += THREADS) {
                const float v = sp[m].w * tot;
                if (v != 0.f) atomicAdd(&ssc_g[b * M_ + m], v);
            }
        }
    } else {
        __syncthreads();
        if (tid == 0) {
            float t = 0.f;
            #pragma unroll
            for (int w = 0; w < WAVES; ++w) t += wcost[w];
            atomicAdd(&out[b], t);
        }
    }
}

extern "C" void kernel_launch(void* const* d_in, const int* in_sizes, int n_in,
                              void* d_out, int out_size, void* d_ws, size_t ws_size,
                              hipStream_t stream) {
    const float* xyz1 = (const float*)d_in[0];
    const float* xyz2 = (const float*)d_in[1];
    float* out = (float*)d_out;
    float* ws = (float*)d_ws;
    const int SZ = B_ * N_;          // == B_*M_ == 16384
    float* rL  = ws;
    float* fb  = ws + SZ;
    float* rRb[2] = { ws + 2*SZ, ws + 3*SZ };
    float* ssb[3] = { ws + 4*SZ, ws + 5*SZ, ws + 6*SZ };
    float2* bounds2 = (float2*)(ws + 7*SZ);
    float4* xyz1s   = (float4*)(ws + 7*SZ + 512);
    float4* xyz2s   = xyz1s + (size_t)B_ * N_;

    init_kernel<<<(SZ + 255) / 256, 256, 0, stream>>>(rL, fb, ssb[0], out);
    sort_kernel<<<2 * B_, 1024, 0, stream>>>(xyz1, xyz2, xyz1s, xyz2s, bounds2);

    constexpr float LOG2E = 1.4426950408889634f;
    static const float levels[10] = {
        -16384.f, -4096.f, -1024.f, -256.f, -64.f,
        -16.f, -4.f, -1.f, -0.25f, 0.f
    };
    for (int s = 0; s <= 10; ++s) {
        const int has_p2 = (s > 0);
        const int has_p1 = (s < 10);
        const int domask = (s <= 8);
        const int lcz    = (s == 9);
        const float lvl  = (s <= 8) ? levels[s] : levels[8];
        const float ascale = (s == 10) ? 1.f : sqrtf(-(lvl * LOG2E));
        const float inva   = 1.f / ascale;
        fused_step<<<GRID, THREADS, 0, stream>>>(
            xyz1s, xyz2s, bounds2, rL, fb,
            rRb[(s + 1) & 1], rRb[s & 1],
            ssb[(s + 2) % 3], ssb[s % 3], ssb[(s + 1) % 3],
            out, ascale, inva, has_p2, has_p1, domask, lcz);
    }
}